// Round 2
// baseline (147.794 us; speedup 1.0000x reference)
//
#include <hip/hip_runtime.h>

#define NP  44
#define B   400000
#define B4  (B / 4)       // 100000 float4 groups per particle
#define BLK 256
#define CPT 4             // float4 chunks per thread

typedef float v2f __attribute__((ext_vector_type(2)));

__device__ __forceinline__ v2f relu2(v2f a) {
    return __builtin_elementwise_max(a, (v2f)0.0f);
}

// Tiny MLP on a PAIR of batch elements packed in a v2f.
// Weights are wave-uniform scalars (live in SGPRs); math should map to
// v_pk_mul_f32 / v_pk_fma_f32 / v_pk_max_f32.
__device__ __forceinline__ v2f mlp_pair(
    const float w1[4], const float w2[8][4],
    const float w3[4][8], const float w4[4], v2f x)
{
#pragma clang fp contract(fast)
    v2f h1[4];
#pragma unroll
    for (int i = 0; i < 4; ++i) h1[i] = relu2(w1[i] * x);

    v2f h2[8];
#pragma unroll
    for (int i = 0; i < 8; ++i) {
        v2f a = w2[i][0] * h1[0];
#pragma unroll
        for (int k = 1; k < 4; ++k) a += w2[i][k] * h1[k];
        h2[i] = relu2(a);
    }

    v2f h3[4];
#pragma unroll
    for (int i = 0; i < 4; ++i) {
        v2f a = w3[i][0] * h2[0];
#pragma unroll
        for (int k = 1; k < 8; ++k) a += w3[i][k] * h2[k];
        h3[i] = relu2(a);
    }

    v2f a = w4[0] * h3[0];
#pragma unroll
    for (int k = 1; k < 4; ++k) a += w4[k] * h3[k];
    return a;
}

__global__ __launch_bounds__(BLK) void fused_mlp_kernel(
    const float* __restrict__ X,    // (NP, 1, B)
    const float* __restrict__ W1,   // (NP, 4, 1)
    const float* __restrict__ W2,   // (NP, 8, 4)
    const float* __restrict__ W3,   // (NP, 4, 8)
    const float* __restrict__ W4,   // (NP, 1, 4)
    float* __restrict__ out)        // (NP, 1, B)
{
    const int l    = blockIdx.y;
    const int base = blockIdx.x * (BLK * CPT) + threadIdx.x;

    // ---- Wave-uniform weight loads -> SGPRs ----
    const float* p1 = W1 + l * 4;
    const float* p2 = W2 + l * 32;
    const float* p3 = W3 + l * 32;
    const float* p4 = W4 + l * 4;

    float w1[4], w2[8][4], w3[4][8], w4[4];
#pragma unroll
    for (int i = 0; i < 4; ++i) w1[i] = p1[i];
#pragma unroll
    for (int i = 0; i < 8; ++i)
#pragma unroll
        for (int k = 0; k < 4; ++k) w2[i][k] = p2[i * 4 + k];
#pragma unroll
    for (int i = 0; i < 4; ++i)
#pragma unroll
        for (int k = 0; k < 8; ++k) w3[i][k] = p3[i * 8 + k];
#pragma unroll
    for (int i = 0; i < 4; ++i) w4[i] = p4[i];

    const float4* Xp = (const float4*)(X + (size_t)l * B);
    float4*       Op = (float4*)(out + (size_t)l * B);

    if ((blockIdx.x + 1) * (BLK * CPT) <= B4) {
        // -------- fast path: all CPT chunks in bounds --------
        float4 xv[CPT];
#pragma unroll
        for (int c = 0; c < CPT; ++c) xv[c] = Xp[base + c * BLK];  // 4 independent loads

        float4 rv[CPT];
#pragma unroll
        for (int c = 0; c < CPT; ++c) {
            v2f p0 = {xv[c].x, xv[c].y};
            v2f p1v = {xv[c].z, xv[c].w};
            v2f r0 = mlp_pair(w1, w2, w3, w4, p0);
            v2f r1 = mlp_pair(w1, w2, w3, w4, p1v);
            rv[c] = make_float4(r0.x, r0.y, r1.x, r1.y);
        }
#pragma unroll
        for (int c = 0; c < CPT; ++c) Op[base + c * BLK] = rv[c];
    } else {
        // -------- tail path: per-chunk bounds check --------
#pragma unroll
        for (int c = 0; c < CPT; ++c) {
            const int idx = base + c * BLK;
            if (idx < B4) {
                float4 xv = Xp[idx];
                v2f p0 = {xv.x, xv.y};
                v2f p1v = {xv.z, xv.w};
                v2f r0 = mlp_pair(w1, w2, w3, w4, p0);
                v2f r1 = mlp_pair(w1, w2, w3, w4, p1v);
                Op[idx] = make_float4(r0.x, r0.y, r1.x, r1.y);
            }
        }
    }
}

extern "C" void kernel_launch(void* const* d_in, const int* in_sizes, int n_in,
                              void* d_out, int out_size, void* d_ws, size_t ws_size,
                              hipStream_t stream) {
    const float* X  = (const float*)d_in[0];
    const float* W1 = (const float*)d_in[1];
    const float* W2 = (const float*)d_in[2];
    const float* W3 = (const float*)d_in[3];
    const float* W4 = (const float*)d_in[4];
    float* out = (float*)d_out;

    dim3 grid((B4 + BLK * CPT - 1) / (BLK * CPT), NP);   // (98, 44)
    fused_mlp_kernel<<<grid, BLK, 0, stream>>>(X, W1, W2, W3, W4, out);
}

// Round 3
// 127.093 us; speedup vs baseline: 1.1629x; 1.1629x over previous
//
#include <hip/hip_runtime.h>

#define NP  44
#define B   400000
#define B4  (B / 4)       // 100000 float4 groups per particle
#define BLK 256
#define CPT 4             // float4 chunks per thread

// The whole bias-free 1->4->8->4->1 ReLU MLP is positively homogeneous in its
// scalar input:  y(x) = gp*x for x>=0,  gn*x for x<0.  Collapse per particle.
__device__ __forceinline__ void collapse_weights(
    const float* __restrict__ p1, const float* __restrict__ p2,
    const float* __restrict__ p3, const float* __restrict__ p4,
    float& gp, float& gn)
{
    float w1p[4], w1n[4];
#pragma unroll
    for (int k = 0; k < 4; ++k) {
        float w = p1[k];
        w1p[k] = fmaxf(w, 0.0f);
        w1n[k] = fminf(w, 0.0f);
    }

    float d2p[8], d2n[8];
#pragma unroll
    for (int i = 0; i < 8; ++i) {
        float ap = 0.0f, an = 0.0f;
#pragma unroll
        for (int k = 0; k < 4; ++k) {
            float w = p2[i * 4 + k];
            ap = fmaf(w, w1p[k], ap);
            an = fmaf(w, w1n[k], an);
        }
        d2p[i] = fmaxf(ap, 0.0f);   // relu branch for x>=0
        d2n[i] = fminf(an, 0.0f);   // relu branch for x<0  (relu(x*c) = x*min(c,0))
    }

    float f3p[4], f3n[4];
#pragma unroll
    for (int j = 0; j < 4; ++j) {
        float ap = 0.0f, an = 0.0f;
#pragma unroll
        for (int i = 0; i < 8; ++i) {
            float w = p3[j * 8 + i];
            ap = fmaf(w, d2p[i], ap);
            an = fmaf(w, d2n[i], an);
        }
        f3p[j] = fmaxf(ap, 0.0f);
        f3n[j] = fminf(an, 0.0f);
    }

    gp = 0.0f; gn = 0.0f;
#pragma unroll
    for (int j = 0; j < 4; ++j) {
        gp = fmaf(p4[j], f3p[j], gp);
        gn = fmaf(p4[j], f3n[j], gn);
    }
}

__global__ __launch_bounds__(BLK) void collapsed_mlp_kernel(
    const float* __restrict__ X,    // (NP, 1, B)
    const float* __restrict__ W1,   // (NP, 4, 1)
    const float* __restrict__ W2,   // (NP, 8, 4)
    const float* __restrict__ W3,   // (NP, 4, 8)
    const float* __restrict__ W4,   // (NP, 1, 4)
    float* __restrict__ out)        // (NP, 1, B)
{
    const int l    = blockIdx.y;
    const int base = blockIdx.x * (BLK * CPT) + threadIdx.x;

    const float4* Xp = (const float4*)(X + (size_t)l * B);
    float4*       Op = (float4*)(out + (size_t)l * B);

    const bool full = (blockIdx.x + 1) * (BLK * CPT) <= B4;

    // Issue the streaming loads first so they overlap the (uniform) collapse math.
    float4 xv[CPT];
    if (full) {
#pragma unroll
        for (int c = 0; c < CPT; ++c) xv[c] = Xp[base + c * BLK];
    }

    // Per-particle collapse — all operands wave-uniform (s_loads), ~150 VALU ops,
    // runs while the X loads are in flight.
    float gp, gn;
    collapse_weights(W1 + l * 4, W2 + l * 32, W3 + l * 32, W4 + l * 4, gp, gn);

    if (full) {
#pragma unroll
        for (int c = 0; c < CPT; ++c) {
            float4 v = xv[c];
            float4 r;
            r.x = v.x * (v.x >= 0.0f ? gp : gn);
            r.y = v.y * (v.y >= 0.0f ? gp : gn);
            r.z = v.z * (v.z >= 0.0f ? gp : gn);
            r.w = v.w * (v.w >= 0.0f ? gp : gn);
            Op[base + c * BLK] = r;
        }
    } else {
#pragma unroll
        for (int c = 0; c < CPT; ++c) {
            const int idx = base + c * BLK;
            if (idx < B4) {
                float4 v = Xp[idx];
                float4 r;
                r.x = v.x * (v.x >= 0.0f ? gp : gn);
                r.y = v.y * (v.y >= 0.0f ? gp : gn);
                r.z = v.z * (v.z >= 0.0f ? gp : gn);
                r.w = v.w * (v.w >= 0.0f ? gp : gn);
                Op[idx] = r;
            }
        }
    }
}

extern "C" void kernel_launch(void* const* d_in, const int* in_sizes, int n_in,
                              void* d_out, int out_size, void* d_ws, size_t ws_size,
                              hipStream_t stream) {
    const float* X  = (const float*)d_in[0];
    const float* W1 = (const float*)d_in[1];
    const float* W2 = (const float*)d_in[2];
    const float* W3 = (const float*)d_in[3];
    const float* W4 = (const float*)d_in[4];
    float* out = (float*)d_out;

    dim3 grid((B4 + BLK * CPT - 1) / (BLK * CPT), NP);   // (98, 44)
    collapsed_mlp_kernel<<<grid, BLK, 0, stream>>>(X, W1, W2, W3, W4, out);
}